// Round 1
// baseline (773.830 us; speedup 1.0000x reference)
//
#include <hip/hip_runtime.h>

#define N_TOKENS 32768
#define K_CODES  1024
#define DIM      256
#define BETA     0.25f

// ---------------- wnorm: wn[k] = sum_d w[k][d]^2 ----------------
__global__ void wnorm_kernel(const float* __restrict__ w, float* __restrict__ wn) {
    int k = blockIdx.x;
    int lane = threadIdx.x;  // 64
    float4 v = *(const float4*)(w + (size_t)k * DIM + lane * 4);
    float s = v.x * v.x + v.y * v.y + v.z * v.z + v.w * v.w;
    #pragma unroll
    for (int off = 32; off; off >>= 1) s += __shfl_down(s, off);
    if (lane == 0) wn[k] = s;
}

// ---------------- argmin: fused distance-GEMM + running argmin ----------------
// block = 256 threads, handles 128 tokens x all 1024 codes (8 k-tiles of 128).
// thread micro-tile: 8 tokens x 8 codes. LDS tiles transposed [d][elem], stride 132
// (16B-aligned rows for ds_read_b128, broken power-of-2 banking).
__global__ __launch_bounds__(256) void argmin_kernel(
    const float* __restrict__ z, const float* __restrict__ w,
    const float* __restrict__ wn, float* __restrict__ idxf,
    int* __restrict__ idxi, int* __restrict__ counts)
{
    constexpr int TM = 128, TK = 128, DC = 32, LS = 132;
    __shared__ float zs[DC * LS];
    __shared__ float wsh[DC * LS];
    __shared__ float wns[TK];
    __shared__ float rv[TM * 16];
    __shared__ int   ri[TM * 16];

    const int tid = threadIdx.x;
    const int ty = tid >> 4;       // 0..15 -> token group
    const int tx = tid & 15;       // 0..15 -> code group
    const int tok0 = blockIdx.x * TM;

    float minv[8];
    int   mini[8];
    #pragma unroll
    for (int i = 0; i < 8; i++) { minv[i] = 3.4e38f; mini[i] = 0; }

    for (int kt = 0; kt < K_CODES / TK; ++kt) {
        const int k0 = kt * TK;
        __syncthreads();   // protect wns (read in previous kt's epilogue)
        if (tid < TK) wns[tid] = wn[k0 + tid];

        float acc[8][8];
        #pragma unroll
        for (int i = 0; i < 8; i++)
            #pragma unroll
            for (int j = 0; j < 8; j++) acc[i][j] = 0.0f;

        for (int dt = 0; dt < DIM / DC; ++dt) {
            const int d0 = dt * DC;
            __syncthreads();   // previous compute phase done before restage
            // stage z tile: 128 tokens x 32 dims, transposed into zs[d][t]
            #pragma unroll
            for (int i = 0; i < 4; i++) {
                int id = tid + i * 256;
                int t = id >> 3;       // token 0..127
                int c = id & 7;        // float4 chunk 0..7
                float4 v = *(const float4*)(z + (size_t)(tok0 + t) * DIM + d0 + c * 4);
                int d = c * 4;
                zs[(d + 0) * LS + t] = v.x;
                zs[(d + 1) * LS + t] = v.y;
                zs[(d + 2) * LS + t] = v.z;
                zs[(d + 3) * LS + t] = v.w;
            }
            // stage w tile: 128 codes x 32 dims, transposed into wsh[d][k]
            #pragma unroll
            for (int i = 0; i < 4; i++) {
                int id = tid + i * 256;
                int t = id >> 3;
                int c = id & 7;
                float4 v = *(const float4*)(w + (size_t)(k0 + t) * DIM + d0 + c * 4);
                int d = c * 4;
                wsh[(d + 0) * LS + t] = v.x;
                wsh[(d + 1) * LS + t] = v.y;
                wsh[(d + 2) * LS + t] = v.z;
                wsh[(d + 3) * LS + t] = v.w;
            }
            __syncthreads();
            #pragma unroll 8
            for (int d = 0; d < DC; ++d) {
                float za[8], wa[8];
                *(float4*)&za[0] = *(const float4*)&zs[d * LS + ty * 8];
                *(float4*)&za[4] = *(const float4*)&zs[d * LS + ty * 8 + 4];
                *(float4*)&wa[0] = *(const float4*)&wsh[d * LS + tx * 8];
                *(float4*)&wa[4] = *(const float4*)&wsh[d * LS + tx * 8 + 4];
                #pragma unroll
                for (int i = 0; i < 8; i++)
                    #pragma unroll
                    for (int j = 0; j < 8; j++)
                        acc[i][j] = fmaf(za[i], wa[j], acc[i][j]);
            }
        }
        // distances (relative: wn - 2*z.w ; ||z||^2 constant per row) + argmin
        #pragma unroll
        for (int j = 0; j < 8; j++) {
            int kk = k0 + tx * 8 + j;
            float wnv = wns[tx * 8 + j];
            #pragma unroll
            for (int i = 0; i < 8; i++) {
                float dist = wnv - 2.0f * acc[i][j];
                if (dist < minv[i]) { minv[i] = dist; mini[i] = kk; }
            }
        }
    }

    // cross-thread (tx) argmin reduction per token row
    #pragma unroll
    for (int i = 0; i < 8; i++) {
        rv[(ty * 8 + i) * 16 + tx] = minv[i];
        ri[(ty * 8 + i) * 16 + tx] = mini[i];
    }
    __syncthreads();
    if (tid < TM) {
        float bv = rv[tid * 16];
        int   bi = ri[tid * 16];
        #pragma unroll
        for (int t = 1; t < 16; t++) {
            float v = rv[tid * 16 + t];
            int   ii = ri[tid * 16 + t];
            if (v < bv || (v == bv && ii < bi)) { bv = v; bi = ii; }
        }
        int tok = tok0 + tid;
        idxi[tok] = bi;
        idxf[tok] = (float)bi;
        atomicAdd(&counts[bi], 1);
    }
}

// ---------------- gather + commitment loss ----------------
__global__ void gather_loss_kernel(const float* __restrict__ z,
                                   const float* __restrict__ w,
                                   const int* __restrict__ idxi,
                                   float* __restrict__ zq_out,
                                   float* __restrict__ loss_acc)
{
    int gid = blockIdx.x * 256 + threadIdx.x;   // float4 index
    int tok = gid >> 6;                          // 64 float4 per token
    int j = gid & 63;
    int k = idxi[tok];
    float4 wv = *(const float4*)(w + (size_t)k * DIM + j * 4);
    float4 zv = *(const float4*)(z + (size_t)gid * 4);
    *(float4*)(zq_out + (size_t)gid * 4) = wv;
    float dx = wv.x - zv.x, dy = wv.y - zv.y, dz = wv.z - zv.z, dw = wv.w - zv.w;
    float s = dx * dx + dy * dy + dz * dz + dw * dw;
    #pragma unroll
    for (int off = 32; off; off >>= 1) s += __shfl_down(s, off);
    if ((threadIdx.x & 63) == 0) atomicAdd(loss_acc, s);
}

// ---------------- perplexity + loss finalize ----------------
__global__ void finalize_kernel(const int* __restrict__ counts,
                                const float* __restrict__ loss_acc,
                                float* __restrict__ loss_out,
                                float* __restrict__ ppl_out)
{
    __shared__ float red[16];
    int tid = threadIdx.x;  // 1024
    float e = (float)counts[tid] * (1.0f / (float)N_TOKENS);
    float t = -e * logf(e + 1e-10f);
    #pragma unroll
    for (int off = 32; off; off >>= 1) t += __shfl_down(t, off);
    if ((tid & 63) == 0) red[tid >> 6] = t;
    __syncthreads();
    if (tid == 0) {
        float s = 0.0f;
        #pragma unroll
        for (int i = 0; i < 16; i++) s += red[i];
        *ppl_out = expf(s);
        *loss_out = BETA * (*loss_acc) / (float)((size_t)N_TOKENS * DIM);
    }
}

extern "C" void kernel_launch(void* const* d_in, const int* in_sizes, int n_in,
                              void* d_out, int out_size, void* d_ws, size_t ws_size,
                              hipStream_t stream) {
    const float* z = (const float*)d_in[0];
    const float* w = (const float*)d_in[1];
    float* out = (float*)d_out;

    // d_out layout (all float): [0]=loss, [1..NT*D]=z_q_st, [..]=indices(float), [last]=perplexity
    float* loss_out = out;
    float* zq_out   = out + 1;
    float* idxf     = out + 1 + (size_t)N_TOKENS * DIM;
    float* ppl_out  = out + (out_size - 1);

    // ws layout: [0..1023] wn (f32) | [1024..2047] counts (i32) | [2048] loss acc (f32) | [2052..] idx (i32)
    float* wn       = (float*)d_ws;
    int*   counts   = (int*)d_ws + 1024;
    float* loss_acc = (float*)d_ws + 2048;
    int*   idxi     = (int*)d_ws + 2052;

    // zero counts + loss accumulator (ws is poisoned 0xAA before every launch)
    hipMemsetAsync((char*)d_ws + 4096, 0, 4100, stream);

    wnorm_kernel<<<K_CODES, 64, 0, stream>>>(w, wn);
    argmin_kernel<<<N_TOKENS / 128, 256, 0, stream>>>(z, w, wn, idxf, idxi, counts);
    gather_loss_kernel<<<(N_TOKENS * DIM / 4) / 256, 256, 0, stream>>>(z, w, idxi, zq_out, loss_acc);
    finalize_kernel<<<1, 1024, 0, stream>>>(counts, loss_acc, loss_out, ppl_out);
}

// Round 2
// 437.366 us; speedup vs baseline: 1.7693x; 1.7693x over previous
//
#include <hip/hip_runtime.h>

#define N_TOKENS 32768
#define K_CODES  1024
#define DIM      256
#define BETA     0.25f

#define SKEW(i) ((i) + 4 * ((i) >> 5))

// ---------------- wnorm: wn[k] = sum_d w[k][d]^2 ----------------
__global__ void wnorm_kernel(const float* __restrict__ w, float* __restrict__ wn) {
    int k = blockIdx.x;
    int lane = threadIdx.x;  // 64
    float4 v = *(const float4*)(w + (size_t)k * DIM + lane * 4);
    float s = v.x * v.x + v.y * v.y + v.z * v.z + v.w * v.w;
    #pragma unroll
    for (int off = 32; off; off >>= 1) s += __shfl_down(s, off);
    if (lane == 0) wn[k] = s;
}

// ---------------- argmin: fused distance-GEMM + running argmin ----------------
// 256 threads/block, block = 128 tokens x 1024 codes (4 kt of 256 codes).
// thread micro-tile: 8 tokens x 16 codes (128 FMA : 6 ds_read_b128).
// LDS transposed [d][elem] with skew k+4*(k>>5): wa reads 2-way (free),
// staging stores 4-way. Register prefetch pipeline hides global latency.
__global__ __launch_bounds__(256, 2) void argmin_kernel(
    const float* __restrict__ z, const float* __restrict__ w,
    const float* __restrict__ wn, float* __restrict__ idxf,
    int* __restrict__ idxi, int* __restrict__ counts)
{
    constexpr int ZLS = 148;   // row stride for z tile rows (128 tokens + skew)
    constexpr int WLS = 292;   // row stride for w tile rows (256 codes + skew)
    __shared__ float smem[32 * ZLS + 32 * WLS];   // 56,320 B
    float* zs  = smem;
    float* wsh = smem + 32 * ZLS;

    const int tid = threadIdx.x;
    const int ty = tid >> 4;      // 0..15 -> 8-token group
    const int tx = tid & 15;      // 0..15 -> 16-code group
    const int tok0 = blockIdx.x * 128;

    const int zoff = SKEW(ty * 8);
    const int woff = tx * 16 + 4 * (tx >> 1);   // SKEW(tx*16)

    float minv[8];
    int   mini[8];
    #pragma unroll
    for (int i = 0; i < 8; i++) { minv[i] = 3.4e38f; mini[i] = 0; }

    // register prefetch buffers: z chunk (128x32) = 4 float4/thread,
    // w chunk (256x32) = 8 float4/thread
    float4 pz[4], pw[8];
    #pragma unroll
    for (int i = 0; i < 4; i++) {
        int id = tid + i * 256; int t = id >> 3, c = id & 7;
        pz[i] = *(const float4*)(z + (size_t)(tok0 + t) * DIM + c * 4);
    }
    #pragma unroll
    for (int i = 0; i < 8; i++) {
        int id = tid + i * 256; int t = id >> 3, c = id & 7;
        pw[i] = *(const float4*)(w + (size_t)t * DIM + c * 4);
    }

    for (int kt = 0; kt < 4; ++kt) {
        float acc[8][16];
        #pragma unroll
        for (int i = 0; i < 8; i++)
            #pragma unroll
            for (int j = 0; j < 16; j++) acc[i][j] = 0.0f;

        for (int dt = 0; dt < 8; ++dt) {
            __syncthreads();   // previous chunk's compute done; LDS reusable
            // store prefetched regs -> LDS (transposed + skewed)
            #pragma unroll
            for (int i = 0; i < 4; i++) {
                int id = tid + i * 256; int t = id >> 3, c = id & 7;
                int st = SKEW(t);
                zs[(c * 4 + 0) * ZLS + st] = pz[i].x;
                zs[(c * 4 + 1) * ZLS + st] = pz[i].y;
                zs[(c * 4 + 2) * ZLS + st] = pz[i].z;
                zs[(c * 4 + 3) * ZLS + st] = pz[i].w;
            }
            #pragma unroll
            for (int i = 0; i < 8; i++) {
                int id = tid + i * 256; int t = id >> 3, c = id & 7;
                int st = SKEW(t);
                wsh[(c * 4 + 0) * WLS + st] = pw[i].x;
                wsh[(c * 4 + 1) * WLS + st] = pw[i].y;
                wsh[(c * 4 + 2) * WLS + st] = pw[i].z;
                wsh[(c * 4 + 3) * WLS + st] = pw[i].w;
            }
            __syncthreads();

            // issue next chunk's global loads (complete during compute below)
            int itn = kt * 8 + dt + 1;
            if (itn < 32) {
                int nk0 = (itn >> 3) * 256, nd0 = (itn & 7) * 32;
                #pragma unroll
                for (int i = 0; i < 4; i++) {
                    int id = tid + i * 256; int t = id >> 3, c = id & 7;
                    pz[i] = *(const float4*)(z + (size_t)(tok0 + t) * DIM + nd0 + c * 4);
                }
                #pragma unroll
                for (int i = 0; i < 8; i++) {
                    int id = tid + i * 256; int t = id >> 3, c = id & 7;
                    pw[i] = *(const float4*)(w + (size_t)(nk0 + t) * DIM + nd0 + c * 4);
                }
            }

            // compute: 32 layers x (8 tok x 16 codes)
            #pragma unroll 8
            for (int d = 0; d < 32; ++d) {
                float za[8], wa[16];
                *(float4*)&za[0] = *(const float4*)&zs[d * ZLS + zoff];
                *(float4*)&za[4] = *(const float4*)&zs[d * ZLS + zoff + 4];
                *(float4*)&wa[0]  = *(const float4*)&wsh[d * WLS + woff];
                *(float4*)&wa[4]  = *(const float4*)&wsh[d * WLS + woff + 4];
                *(float4*)&wa[8]  = *(const float4*)&wsh[d * WLS + woff + 8];
                *(float4*)&wa[12] = *(const float4*)&wsh[d * WLS + woff + 12];
                #pragma unroll
                for (int i = 0; i < 8; i++)
                    #pragma unroll
                    for (int j = 0; j < 16; j++)
                        acc[i][j] = fmaf(za[i], wa[j], acc[i][j]);
            }
        }

        // epilogue: relative distance wn - 2*z.w, running argmin
        int k0 = kt * 256;
        float wnv[16];
        #pragma unroll
        for (int u = 0; u < 4; u++)
            *(float4*)&wnv[u * 4] = *(const float4*)(wn + k0 + tx * 16 + u * 4);
        #pragma unroll
        for (int j = 0; j < 16; j++) {
            int kk = k0 + tx * 16 + j;
            #pragma unroll
            for (int i = 0; i < 8; i++) {
                float dist = wnv[j] - 2.0f * acc[i][j];
                if (dist < minv[i]) { minv[i] = dist; mini[i] = kk; }
            }
        }
    }

    // cross-thread (tx) argmin reduction per token row (alias LDS)
    __syncthreads();
    float* rv = smem;                       // 128*16 floats
    int*   ri = (int*)(smem + 2048);        // 128*16 ints
    #pragma unroll
    for (int i = 0; i < 8; i++) {
        rv[(ty * 8 + i) * 16 + tx] = minv[i];
        ri[(ty * 8 + i) * 16 + tx] = mini[i];
    }
    __syncthreads();
    if (tid < 128) {
        float bv = rv[tid * 16];
        int   bi = ri[tid * 16];
        #pragma unroll
        for (int t = 1; t < 16; t++) {
            float v = rv[tid * 16 + t];
            int  ii = ri[tid * 16 + t];
            if (v < bv || (v == bv && ii < bi)) { bv = v; bi = ii; }
        }
        int tok = tok0 + tid;
        idxi[tok] = bi;
        idxf[tok] = (float)bi;
        atomicAdd(&counts[bi], 1);
    }
}

// ---------------- gather + commitment loss (no global atomics) ----------------
__global__ void gather_loss_kernel(const float* __restrict__ z,
                                   const float* __restrict__ w,
                                   const int* __restrict__ idxi,
                                   float* __restrict__ zq_out,
                                   float* __restrict__ partials)
{
    __shared__ float red[4];
    int tid = threadIdx.x;
    int gid0 = blockIdx.x * 256 + tid;
    float s = 0.0f;
    #pragma unroll
    for (int it = 0; it < 8; it++) {
        int g = gid0 + it * (1024 * 256);     // float4 index, 2,097,152 total
        int tok = g >> 6;
        int j = g & 63;
        int k = idxi[tok];
        float4 wv = *(const float4*)(w + (size_t)k * DIM + j * 4);
        float4 zv = *(const float4*)(z + (size_t)g * 4);
        *(float4*)(zq_out + (size_t)g * 4) = wv;
        float dx = wv.x - zv.x, dy = wv.y - zv.y, dz = wv.z - zv.z, dw = wv.w - zv.w;
        s += dx * dx + dy * dy + dz * dz + dw * dw;
    }
    #pragma unroll
    for (int off = 32; off; off >>= 1) s += __shfl_down(s, off);
    if ((tid & 63) == 0) red[tid >> 6] = s;
    __syncthreads();
    if (tid == 0)
        partials[blockIdx.x] = red[0] + red[1] + red[2] + red[3];
}

// ---------------- perplexity + loss finalize ----------------
__global__ void finalize_kernel(const int* __restrict__ counts,
                                const float* __restrict__ partials,
                                float* __restrict__ loss_out,
                                float* __restrict__ ppl_out)
{
    __shared__ float redE[16], redL[16];
    int tid = threadIdx.x;  // 1024
    float e = (float)counts[tid] * (1.0f / (float)N_TOKENS);
    float t = -e * logf(e + 1e-10f);
    float p = partials[tid];
    #pragma unroll
    for (int off = 32; off; off >>= 1) {
        t += __shfl_down(t, off);
        p += __shfl_down(p, off);
    }
    if ((tid & 63) == 0) { redE[tid >> 6] = t; redL[tid >> 6] = p; }
    __syncthreads();
    if (tid == 0) {
        float se = 0.0f, sl = 0.0f;
        #pragma unroll
        for (int i = 0; i < 16; i++) { se += redE[i]; sl += redL[i]; }
        *ppl_out = expf(se);
        *loss_out = BETA * sl / (float)((size_t)N_TOKENS * DIM);
    }
}

extern "C" void kernel_launch(void* const* d_in, const int* in_sizes, int n_in,
                              void* d_out, int out_size, void* d_ws, size_t ws_size,
                              hipStream_t stream) {
    const float* z = (const float*)d_in[0];
    const float* w = (const float*)d_in[1];
    float* out = (float*)d_out;

    // d_out layout (all float): [0]=loss, [1..NT*D]=z_q_st, [..]=indices(float), [last]=perplexity
    float* loss_out = out;
    float* zq_out   = out + 1;
    float* idxf     = out + 1 + (size_t)N_TOKENS * DIM;
    float* ppl_out  = out + (out_size - 1);

    // ws layout: [0..1023] wn f32 | [1024..2047] counts i32 | [2048..3071] partials f32 | [3072..] idx i32
    float* wn       = (float*)d_ws;
    int*   counts   = (int*)d_ws + 1024;
    float* partials = (float*)d_ws + 2048;
    int*   idxi     = (int*)d_ws + 3072;

    // zero counts only (partials are overwritten unconditionally)
    hipMemsetAsync((char*)d_ws + 4096, 0, 4096, stream);

    wnorm_kernel<<<K_CODES, 64, 0, stream>>>(w, wn);
    argmin_kernel<<<N_TOKENS / 128, 256, 0, stream>>>(z, w, wn, idxf, idxi, counts);
    gather_loss_kernel<<<1024, 256, 0, stream>>>(z, w, idxi, zq_out, partials);
    finalize_kernel<<<1, 1024, 0, stream>>>(counts, partials, loss_out, ppl_out);
}

// Round 3
// 332.144 us; speedup vs baseline: 2.3298x; 1.3168x over previous
//
#include <hip/hip_runtime.h>

#define N_TOKENS 32768
#define K_CODES  1024
#define DIM      256
#define BETA     0.25f

// ---------------- wnorm: wn[k] = sum_d w[k][d]^2 ----------------
__global__ void wnorm_kernel(const float* __restrict__ w, float* __restrict__ wn) {
    int k = blockIdx.x;
    int lane = threadIdx.x;  // 64
    float4 v = *(const float4*)(w + (size_t)k * DIM + lane * 4);
    float s = v.x * v.x + v.y * v.y + v.z * v.z + v.w * v.w;
    #pragma unroll
    for (int off = 32; off; off >>= 1) s += __shfl_down(s, off);
    if (lane == 0) wn[k] = s;
}

// ---------------- argmin: split-K fused distance-GEMM + atomicMin merge ----
// grid = 256 token-tiles x 4 code-quarters. Block: 128 tokens x 256 codes
// (2 slabs of 128 codes), 256 threads, micro-tile 8x8 (acc=64 regs).
// LDS transposed [d][elem]: ZLS=140 / WLS=148 (both ==4 mod 8) with
// row-group shift 8*((c>>1)&1) -> transpose stores 2-way (free);
// code-skew 4*((k>>5)&3) -> wa reads 2-way (free).
// Blocks merge per-token argmin via atomicMin on (sortable_dist<<32)|idx.
__global__ __launch_bounds__(256, 3) void argmin_kernel(
    const float* __restrict__ z, const float* __restrict__ w,
    const float* __restrict__ wn, unsigned long long* __restrict__ keys)
{
    constexpr int ZLS = 140, WLS = 148;
    __shared__ float zs[32 * ZLS];    // 17,920 B
    __shared__ float wsh[32 * WLS];   // 18,944 B

    const int tid = threadIdx.x;
    const int ty = tid >> 4;          // 0..15 -> 8-token group
    const int tx = tid & 15;          // 0..15 -> 8-code group (within slab)
    const int tile = blockIdx.x >> 2;
    const int q    = blockIdx.x & 3;
    const int tok0  = tile * 128;
    const int kbase = q * 256;

    const int zoffb = ty * 8;
    const int woffb = tx * 8 + 4 * ((tx >> 2) & 3);

    float minv[8];
    int   mini[8];
    #pragma unroll
    for (int i = 0; i < 8; i++) { minv[i] = 3.4e38f; mini[i] = 0; }

    // prefetch regs: z chunk 128x32 -> 4 float4/thread; w chunk 128x32 -> 4 float4/thread
    float4 pz[4], pw[4];
    #pragma unroll
    for (int i = 0; i < 4; i++) {
        int id = tid + i * 256; int t = id >> 3, c = id & 7;
        pz[i] = *(const float4*)(z + (size_t)(tok0 + t) * DIM + c * 4);
        pw[i] = *(const float4*)(w + (size_t)(kbase + t) * DIM + c * 4);
    }

    for (int kt = 0; kt < 2; ++kt) {
        float acc[8][8];
        #pragma unroll
        for (int i = 0; i < 8; i++)
            #pragma unroll
            for (int j = 0; j < 8; j++) acc[i][j] = 0.0f;

        for (int dt = 0; dt < 8; ++dt) {
            __syncthreads();   // previous chunk's LDS reads done
            // transpose-store prefetched regs (2-way conflict = free)
            #pragma unroll
            for (int i = 0; i < 4; i++) {
                int id = tid + i * 256; int t = id >> 3, c = id & 7;
                int zc = t + 8 * ((c >> 1) & 1);
                zs[(c * 4 + 0) * ZLS + zc] = pz[i].x;
                zs[(c * 4 + 1) * ZLS + zc] = pz[i].y;
                zs[(c * 4 + 2) * ZLS + zc] = pz[i].z;
                zs[(c * 4 + 3) * ZLS + zc] = pz[i].w;
                int wc = t + 4 * ((t >> 5) & 3) + 8 * ((c >> 1) & 1);
                wsh[(c * 4 + 0) * WLS + wc] = pw[i].x;
                wsh[(c * 4 + 1) * WLS + wc] = pw[i].y;
                wsh[(c * 4 + 2) * WLS + wc] = pw[i].z;
                wsh[(c * 4 + 3) * WLS + wc] = pw[i].w;
            }
            __syncthreads();

            // issue next chunk's global loads (in flight during compute)
            int it2 = kt * 8 + dt + 1;
            if (it2 < 16) {
                int nk0 = kbase + (it2 >> 3) * 128;
                int nd0 = (it2 & 7) * 32;
                #pragma unroll
                for (int i = 0; i < 4; i++) {
                    int id = tid + i * 256; int t = id >> 3, c = id & 7;
                    pz[i] = *(const float4*)(z + (size_t)(tok0 + t) * DIM + nd0 + c * 4);
                    pw[i] = *(const float4*)(w + (size_t)(nk0 + t) * DIM + nd0 + c * 4);
                }
            }

            // compute: 32 layers x (8 tok x 8 codes)
            #pragma unroll 8
            for (int d = 0; d < 32; ++d) {
                float za[8], wa[8];
                int sh = 8 * ((d >> 3) & 1);
                *(float4*)&za[0] = *(const float4*)&zs[d * ZLS + sh + zoffb];
                *(float4*)&za[4] = *(const float4*)&zs[d * ZLS + sh + zoffb + 4];
                *(float4*)&wa[0] = *(const float4*)&wsh[d * WLS + sh + woffb];
                *(float4*)&wa[4] = *(const float4*)&wsh[d * WLS + sh + woffb + 4];
                #pragma unroll
                for (int i = 0; i < 8; i++)
                    #pragma unroll
                    for (int j = 0; j < 8; j++)
                        acc[i][j] = fmaf(za[i], wa[j], acc[i][j]);
            }
        }

        // epilogue: dist = wn - 2*z.w (||z||^2 constant per row), running argmin
        int k0 = kbase + kt * 128;
        float wnv[8];
        *(float4*)&wnv[0] = *(const float4*)(wn + k0 + tx * 8);
        *(float4*)&wnv[4] = *(const float4*)(wn + k0 + tx * 8 + 4);
        #pragma unroll
        for (int j = 0; j < 8; j++) {
            int kk = k0 + tx * 8 + j;
            #pragma unroll
            for (int i = 0; i < 8; i++) {
                float dist = wnv[j] - 2.0f * acc[i][j];
                if (dist < minv[i]) { minv[i] = dist; mini[i] = kk; }
            }
        }
    }

    // cross-thread (tx) argmin reduction per token row (alias LDS)
    __syncthreads();
    float* rv = zs;                 // 128*16 floats = 8192 B
    int*   ri = (int*)wsh;          // 128*16 ints
    #pragma unroll
    for (int i = 0; i < 8; i++) {
        rv[(ty * 8 + i) * 16 + tx] = minv[i];
        ri[(ty * 8 + i) * 16 + tx] = mini[i];
    }
    __syncthreads();
    if (tid < 128) {
        float bv = rv[tid * 16];
        int   bi = ri[tid * 16];
        #pragma unroll
        for (int t = 1; t < 16; t++) {
            float v = rv[tid * 16 + t];
            int  ii = ri[tid * 16 + t];
            if (v < bv || (v == bv && ii < bi)) { bv = v; bi = ii; }
        }
        // pack sortable key: monotone encode of float, idx in low bits
        unsigned u = __float_as_uint(bv);
        unsigned s = (u & 0x80000000u) ? ~u : (u | 0x80000000u);
        unsigned long long key = ((unsigned long long)s << 32) | (unsigned)bi;
        atomicMin(&keys[tok0 + tid], key);
    }
}

// ---------------- gather + commitment loss + idx/counts ----------------
// wave (64 lanes) = exactly one token (64 float4). 4096 waves x 8 iters.
__global__ void gather_loss_kernel(const float* __restrict__ z,
                                   const float* __restrict__ w,
                                   const unsigned long long* __restrict__ keys,
                                   float* __restrict__ zq_out,
                                   float* __restrict__ idxf,
                                   int* __restrict__ counts,
                                   float* __restrict__ partials)
{
    __shared__ float red[4];
    int tid = threadIdx.x;
    int lane = tid & 63;
    int wid = blockIdx.x * 4 + (tid >> 6);   // global wave id 0..4095
    float s = 0.0f;
    #pragma unroll
    for (int it = 0; it < 8; it++) {
        int tok = wid + it * 4096;
        unsigned long long key = 0;
        if (lane == 0) key = keys[tok];
        key = __shfl(key, 0);
        int k = (int)(unsigned)(key & 0xFFFFFFFFull);
        float4 wv = *(const float4*)(w + (size_t)k * DIM + lane * 4);
        float4 zv = *(const float4*)(z + (size_t)tok * DIM + lane * 4);
        *(float4*)(zq_out + (size_t)tok * DIM + lane * 4) = wv;
        float dx = wv.x - zv.x, dy = wv.y - zv.y, dz = wv.z - zv.z, dw = wv.w - zv.w;
        s += dx * dx + dy * dy + dz * dz + dw * dw;
        if (lane == 0) {
            idxf[tok] = (float)k;
            atomicAdd(&counts[k], 1);
        }
    }
    #pragma unroll
    for (int off = 32; off; off >>= 1) s += __shfl_down(s, off);
    if (lane == 0) red[tid >> 6] = s;
    __syncthreads();
    if (tid == 0)
        partials[blockIdx.x] = red[0] + red[1] + red[2] + red[3];
}

// ---------------- perplexity + loss finalize ----------------
__global__ void finalize_kernel(const int* __restrict__ counts,
                                const float* __restrict__ partials,
                                float* __restrict__ loss_out,
                                float* __restrict__ ppl_out)
{
    __shared__ float redE[16], redL[16];
    int tid = threadIdx.x;  // 1024
    float e = (float)counts[tid] * (1.0f / (float)N_TOKENS);
    float t = -e * logf(e + 1e-10f);
    float p = partials[tid];
    #pragma unroll
    for (int off = 32; off; off >>= 1) {
        t += __shfl_down(t, off);
        p += __shfl_down(p, off);
    }
    if ((tid & 63) == 0) { redE[tid >> 6] = t; redL[tid >> 6] = p; }
    __syncthreads();
    if (tid == 0) {
        float se = 0.0f, sl = 0.0f;
        #pragma unroll
        for (int i = 0; i < 16; i++) { se += redE[i]; sl += redL[i]; }
        *ppl_out = expf(se);
        *loss_out = BETA * sl / (float)((size_t)N_TOKENS * DIM);
    }
}

extern "C" void kernel_launch(void* const* d_in, const int* in_sizes, int n_in,
                              void* d_out, int out_size, void* d_ws, size_t ws_size,
                              hipStream_t stream) {
    const float* z = (const float*)d_in[0];
    const float* w = (const float*)d_in[1];
    float* out = (float*)d_out;

    // d_out layout (float): [0]=loss, [1..NT*D]=z_q_st, [..]=indices(float), [last]=perplexity
    float* loss_out = out;
    float* zq_out   = out + 1;
    float* idxf     = out + 1 + (size_t)N_TOKENS * DIM;
    float* ppl_out  = out + (out_size - 1);

    // ws layout (float idx): wn[0..1023] | counts[1024..2047] | partials[2048..3071]
    //                        | keys (u64) at float offset 4096 (byte 16384)
    float* wn       = (float*)d_ws;
    int*   counts   = (int*)d_ws + 1024;
    float* partials = (float*)d_ws + 2048;
    unsigned long long* keys = (unsigned long long*)((char*)d_ws + 16384);

    hipMemsetAsync(counts, 0, 4096, stream);
    hipMemsetAsync(keys, 0xFF, (size_t)N_TOKENS * 8, stream);

    wnorm_kernel<<<K_CODES, 64, 0, stream>>>(w, wn);
    argmin_kernel<<<(N_TOKENS / 128) * 4, 256, 0, stream>>>(z, w, wn, keys);
    gather_loss_kernel<<<1024, 256, 0, stream>>>(z, w, keys, zq_out, idxf, counts, partials);
    finalize_kernel<<<1, 1024, 0, stream>>>(counts, partials, loss_out, ppl_out);
}